// Round 1
// baseline (631.779 us; speedup 1.0000x reference)
//
#include <hip/hip_runtime.h>

#define NB 147456   // C*C*KH*KW
#define ZD 256
#define BSZ 32
#define CCH 128
#define HWD 32

// Kernel 1: h = relu(z @ dense_w + dense_b); batch-norm over axis 0; affine.
// One thread per output column n (147456 total). All 32 batch values live in
// registers, so the batch-norm fuses for free.
__global__ __launch_bounds__(256) void hyper_gemm_bn(
    const float* __restrict__ z,      // (32,256)
    const float* __restrict__ dw,     // (256, NB)
    const float* __restrict__ db,     // (NB)
    const float* __restrict__ gamma,  // (NB)
    const float* __restrict__ beta,   // (NB)
    float* __restrict__ wk)           // out: (32, NB)
{
    __shared__ float zs[ZD * BSZ];    // transposed: zs[k*32 + b]
    int tid = threadIdx.x;
    for (int i = tid; i < ZD * BSZ; i += 256) {
        int b = i >> 8, k = i & 255;
        zs[k * 32 + b] = z[i];
    }
    __syncthreads();

    int n = blockIdx.x * 256 + tid;   // grid sized exactly: 576*256 = 147456
    float acc[32];
#pragma unroll
    for (int b = 0; b < 32; b++) acc[b] = 0.f;

    const float4* zs4 = (const float4*)zs;
    for (int k0 = 0; k0 < ZD; k0 += 8) {
        float w[8];
#pragma unroll
        for (int j = 0; j < 8; j++)
            w[j] = dw[(size_t)(k0 + j) * NB + n];   // coalesced; 8 loads in flight
#pragma unroll
        for (int j = 0; j < 8; j++) {
#pragma unroll
            for (int bb = 0; bb < 8; bb++) {
                float4 zv = zs4[(k0 + j) * 8 + bb]; // broadcast read
                acc[bb * 4 + 0] += zv.x * w[j];
                acc[bb * 4 + 1] += zv.y * w[j];
                acc[bb * 4 + 2] += zv.z * w[j];
                acc[bb * 4 + 3] += zv.w * w[j];
            }
        }
    }

    float bias = db[n];
    float sum = 0.f, sumsq = 0.f;
#pragma unroll
    for (int b = 0; b < 32; b++) {
        float h = fmaxf(acc[b] + bias, 0.f);
        acc[b] = h;
        sum += h;
        sumsq += h * h;
    }
    float mean = sum * (1.f / 32.f);
    float var = fmaxf(sumsq * (1.f / 32.f) - mean * mean, 0.f);
    float scale = gamma[n] / (sqrtf(var) + 1e-6f);   // ref: gamma*(h-mean)/(std+eps)+beta
    float bt = beta[n];
#pragma unroll
    for (int b = 0; b < 32; b++)
        wk[(size_t)b * NB + n] = scale * (acc[b] - mean) + bt;
}

// Kernel 2: per-sample 3x3 conv (cross-correlation), 128->128 ch, pad 1,
// out[b,f,p,q] = sum_{s,u,v} x[b,s,p+u-1,q+v-1] * Wk[b,s,f,u,v] + bias[f] + x[b,f,p,q]
// Block = (sample b, 8 output channels). x-plane staged in LDS with zero halo;
// rolling 3-row window in registers.
__global__ __launch_bounds__(256) void conv_residual(
    const float* __restrict__ x,    // (32,128,32,32)
    const float* __restrict__ wk,   // (32, NB): [b][s*1152 + f*9 + u*3+v]
    const float* __restrict__ cb,   // (128)
    float* __restrict__ out)        // (32,128,32,32)
{
    __shared__ float xs[34 * 34];
    __shared__ float wl[8 * 9];
    int tid = threadIdx.x;
    int b = blockIdx.x;
    int f0 = blockIdx.y * 8;

    for (int i = tid; i < 34 * 34; i += 256) xs[i] = 0.f;   // zero halo, once

    int fl = tid >> 5;    // 0..7 local output channel
    int q = tid & 31;     // output column
    float acc[32];
#pragma unroll
    for (int p = 0; p < 32; p++) acc[p] = 0.f;

    const float* xb = x + (size_t)b * CCH * HWD * HWD;
    const float* wb = wk + (size_t)b * NB;

    for (int s = 0; s < CCH; s++) {
        __syncthreads();   // protect previous iteration's reads (and halo init at s=0)
        const float* xp = xb + s * HWD * HWD;
        for (int i = tid; i < HWD * HWD; i += 256) {
            int r = i >> 5, c = i & 31;
            xs[(r + 1) * 34 + (c + 1)] = xp[i];
        }
        if (tid < 72) wl[tid] = wb[s * 1152 + f0 * 9 + tid];
        __syncthreads();

        float w0 = wl[fl * 9 + 0], w1 = wl[fl * 9 + 1], w2 = wl[fl * 9 + 2];
        float w3 = wl[fl * 9 + 3], w4 = wl[fl * 9 + 4], w5 = wl[fl * 9 + 5];
        float w6 = wl[fl * 9 + 6], w7 = wl[fl * 9 + 7], w8 = wl[fl * 9 + 8];

        float a0 = xs[0 * 34 + q], a1 = xs[0 * 34 + q + 1], a2 = xs[0 * 34 + q + 2];
        float b0 = xs[1 * 34 + q], b1 = xs[1 * 34 + q + 1], b2 = xs[1 * 34 + q + 2];
#pragma unroll
        for (int p = 0; p < 32; p++) {
            float c0 = xs[(p + 2) * 34 + q];
            float c1 = xs[(p + 2) * 34 + q + 1];
            float c2 = xs[(p + 2) * 34 + q + 2];
            acc[p] += a0 * w0 + a1 * w1 + a2 * w2
                    + b0 * w3 + b1 * w4 + b2 * w5
                    + c0 * w6 + c1 * w7 + c2 * w8;
            a0 = b0; a1 = b1; a2 = b2;
            b0 = c0; b1 = c1; b2 = c2;
        }
    }

    int f = f0 + fl;
    const float* xr = xb + (size_t)f * HWD * HWD;   // residual
    float bf = cb[f];
    float* op = out + ((size_t)b * CCH + f) * HWD * HWD;
#pragma unroll
    for (int p = 0; p < 32; p++)
        op[p * 32 + q] = acc[p] + xr[p * 32 + q] + bf;
}

extern "C" void kernel_launch(void* const* d_in, const int* in_sizes, int n_in,
                              void* d_out, int out_size, void* d_ws, size_t ws_size,
                              hipStream_t stream) {
    const float* x     = (const float*)d_in[0];
    const float* z     = (const float*)d_in[1];
    const float* dw    = (const float*)d_in[2];
    const float* db    = (const float*)d_in[3];
    const float* gamma = (const float*)d_in[4];
    const float* beta  = (const float*)d_in[5];
    const float* cb    = (const float*)d_in[6];
    float* out = (float*)d_out;
    float* wkv = (float*)d_ws;   // 32*147456 floats = 18.9 MB scratch

    hyper_gemm_bn<<<NB / 256, 256, 0, stream>>>(z, dw, db, gamma, beta, wkv);
    conv_residual<<<dim3(BSZ, CCH / 8), 256, 0, stream>>>(x, wkv, cb, out);
}

// Round 2
// 334.298 us; speedup vs baseline: 1.8899x; 1.8899x over previous
//
#include <hip/hip_runtime.h>

#define NB 147456   // C*C*KH*KW per sample
#define ZD 256
#define BSZ 32
#define CCH 128

typedef __attribute__((ext_vector_type(8))) short short8;
typedef __attribute__((ext_vector_type(16))) float floatx16;

__device__ __forceinline__ unsigned short f2bf(float f) {
    unsigned int u = __float_as_uint(f);
    return (unsigned short)((u + 0x7fffu + ((u >> 16) & 1u)) >> 16);
}

// ---------------- Kernel 1: h = relu(z@W+b); BN over batch; affine; -> bf16 Wk (natural [b][n]) ----
// 2 columns per thread: z float4 LDS broadcasts amortized over 2 cols (128 FMA vs 96 LDS-cyc per k).
__global__ __launch_bounds__(128) void hyper_gemm_bn(
    const float* __restrict__ z, const float* __restrict__ dw,
    const float* __restrict__ db, const float* __restrict__ gamma,
    const float* __restrict__ beta, unsigned short* __restrict__ wkn)
{
    __shared__ float zs[ZD * 36];   // zs[k*36 + b], padded for alignment
    int t = threadIdx.x;
    for (int i = 0; i < 16; i++) {
        int i4 = t + i * 128;                  // 2048 float4 total
        int bb = i4 >> 6;                      // batch row (64 float4 per row)
        int k4 = (i4 & 63) << 2;
        float4 v = ((const float4*)z)[i4];
        zs[(k4 + 0) * 36 + bb] = v.x;
        zs[(k4 + 1) * 36 + bb] = v.y;
        zs[(k4 + 2) * 36 + bb] = v.z;
        zs[(k4 + 3) * 36 + bb] = v.w;
    }
    __syncthreads();

    int n0 = (blockIdx.x * 128 + t) * 2;       // 576 blocks * 256 cols = NB
    float acc0[32], acc1[32];
#pragma unroll
    for (int b = 0; b < 32; b++) { acc0[b] = 0.f; acc1[b] = 0.f; }

    const float2* dw2 = (const float2*)dw;
    size_t ncol2 = (size_t)(n0 >> 1);
    for (int k0 = 0; k0 < ZD; k0 += 8) {
        float2 w[8];
#pragma unroll
        for (int j = 0; j < 8; j++)
            w[j] = dw2[(size_t)(k0 + j) * (NB / 2) + ncol2];   // coalesced 8B/lane
#pragma unroll
        for (int j = 0; j < 8; j++) {
            const float* zr = &zs[(k0 + j) * 36];
#pragma unroll
            for (int b4 = 0; b4 < 8; b4++) {
                float4 zv = *(const float4*)(zr + b4 * 4);
                acc0[b4*4+0] += zv.x * w[j].x;  acc1[b4*4+0] += zv.x * w[j].y;
                acc0[b4*4+1] += zv.y * w[j].x;  acc1[b4*4+1] += zv.y * w[j].y;
                acc0[b4*4+2] += zv.z * w[j].x;  acc1[b4*4+2] += zv.z * w[j].y;
                acc0[b4*4+3] += zv.w * w[j].x;  acc1[b4*4+3] += zv.w * w[j].y;
            }
        }
    }

    float bias0 = db[n0], bias1 = db[n0 + 1];
    float s0 = 0.f, q0 = 0.f, s1 = 0.f, q1 = 0.f;
#pragma unroll
    for (int b = 0; b < 32; b++) {
        float h0 = fmaxf(acc0[b] + bias0, 0.f); acc0[b] = h0; s0 += h0; q0 += h0 * h0;
        float h1 = fmaxf(acc1[b] + bias1, 0.f); acc1[b] = h1; s1 += h1; q1 += h1 * h1;
    }
    float m0 = s0 * (1.f/32.f), m1 = s1 * (1.f/32.f);
    float v0 = fmaxf(q0 * (1.f/32.f) - m0 * m0, 0.f);
    float v1 = fmaxf(q1 * (1.f/32.f) - m1 * m1, 0.f);
    float sc0 = gamma[n0]     / (sqrtf(v0) + 1e-6f), bt0 = beta[n0];
    float sc1 = gamma[n0 + 1] / (sqrtf(v1) + 1e-6f), bt1 = beta[n0 + 1];

    unsigned int* wout = (unsigned int*)wkn;
#pragma unroll
    for (int b = 0; b < 32; b++) {
        float w0 = sc0 * (acc0[b] - m0) + bt0;
        float w1 = sc1 * (acc1[b] - m1) + bt1;
        wout[((size_t)b * NB + n0) >> 1] = (unsigned int)f2bf(w0) | ((unsigned int)f2bf(w1) << 16);
    }
}

// ---------------- Repack: Wk_n[b][s*1152 + f*9 + uv] (bf16) -> Wk_t[b][uv][f][s] (bf16) ----------
__global__ __launch_bounds__(256) void repack(
    const unsigned short* __restrict__ wkn, unsigned short* __restrict__ wkt)
{
    __shared__ unsigned short lt[288 * 66];   // [fl*9+uv][si], pad 66 (33 dwords, conflict-free)
    int t = threadIdx.x;
    int b = blockIdx.x;
    int s0 = (blockIdx.y >> 2) * 64;
    int f0 = (blockIdx.y & 3) * 32;
    const size_t inb = (size_t)b * NB;
#pragma unroll 4
    for (int i = 0; i < 72; i++) {
        int idx = t + i * 256;                // 18432 elements
        int si = idx / 288;
        int j = idx - si * 288;               // j = fl*9 + uv
        int fl = j / 9, uv = j - fl * 9;
        lt[j * 66 + si] = wkn[inb + (size_t)(s0 + si) * 1152 + (f0 + fl) * 9 + uv];
    }
    __syncthreads();
#pragma unroll 4
    for (int i = 0; i < 72; i++) {
        int idx = t + i * 256;
        int r = idx >> 6;                     // 0..287 = uv*32 + fl (out order)
        int sl = idx & 63;
        int uv = r >> 5, fl = r & 31;
        wkt[(((size_t)b * 9 + uv) * 128 + (f0 + fl)) * 128 + s0 + sl] = lt[(fl * 9 + uv) * 66 + sl];
    }
}

// ---------------- Kernel 2: per-sample conv as 9 MFMA GEMMs + residual ---------------------------
// out[b,f,p,q] = sum_uv sum_s Wuv[f,s] * x[b,s,p+u-1,q+v-1] + cb[f] + x[b,f,p,q]
// Block: 128 thr = 2 waves; wave = 64f x 64pix (2x2 of 32x32x16 bf16 MFMA); block = 128f x 2 rows.
__global__ __launch_bounds__(128) void conv_mfma(
    const float* __restrict__ x, const unsigned short* __restrict__ wkt,
    const float* __restrict__ cb, float* __restrict__ out)
{
    __shared__ short8 lds8[680];              // x tile: [row 0..3][col 0..33][s 0..31 pad 40] bf16
    unsigned short* lds = (unsigned short*)lds8;
    int t = threadIdx.x;
    int b = blockIdx.x;                       // sample
    int p0 = blockIdx.y * 2;                  // image row pair
    int lane = t & 63;
    int fbase = (t >> 6) * 64;                // wave f base
    int qcol = lane & 31;
    int klane = lane >> 5;                    // 0/1: k-half of the MFMA fragment

    floatx16 acc[2][2];
#pragma unroll
    for (int mi = 0; mi < 2; mi++)
#pragma unroll
        for (int ni = 0; ni < 2; ni++)
#pragma unroll
            for (int r = 0; r < 16; r++) acc[mi][ni][r] = 0.f;

    { // zero LDS once (halo cols 0/33 and out-of-range rows stay zero forever)
        int* ldsi = (int*)lds8;
        for (int i = t; i < 2720; i += 128) ldsi[i] = 0;
    }

    const size_t xb = (size_t)b * CCH * 1024;
    const short8* A8 = (const short8*)wkt;

    for (int sc = 0; sc < 4; sc++) {
        int s0 = sc * 32;
        __syncthreads();
        // stage x[s0..s0+31][p0-1..p0+2][0..31] fp32 -> bf16 LDS (1 KB contiguous per wave-read)
#pragma unroll
        for (int i = 0; i < 8; i++) {
            int g = t + i * 128;              // 1024 float4
            int si = g >> 5;
            int rem = g & 31;
            int row = rem >> 3;               // 0..3
            int fq = rem & 7;                 // float4 within image row
            int prow = p0 - 1 + row;
            float4 v = make_float4(0.f, 0.f, 0.f, 0.f);
            if (prow >= 0 && prow < 32)
                v = *(const float4*)(x + xb + (size_t)(s0 + si) * 1024 + prow * 32 + fq * 4);
            unsigned short* dst = lds + (row * 34 + fq * 4 + 1) * 40 + si;
            dst[0]   = f2bf(v.x);
            dst[40]  = f2bf(v.y);
            dst[80]  = f2bf(v.z);
            dst[120] = f2bf(v.w);
        }
        __syncthreads();

#pragma unroll
        for (int u = 0; u < 3; u++)
#pragma unroll
        for (int v = 0; v < 3; v++) {
            int uvi = u * 3 + v;
            size_t abase = ((size_t)(b * 9 + uvi) * 128) * 16;  // short8 units per f-row = 16
#pragma unroll
            for (int ks = 0; ks < 2; ks++) {
                int koff = (s0 >> 3) + ks * 2 + klane;
                short8 a0 = A8[abase + (size_t)(fbase + qcol) * 16 + koff];
                short8 a1 = A8[abase + (size_t)(fbase + 32 + qcol) * 16 + koff];
                int bb = (qcol + v) * 5 + klane + ks * 2;
                short8 b0 = lds8[u * 170 + bb];          // ni=0: lds row = u+0
                short8 b1 = lds8[(u + 1) * 170 + bb];    // ni=1: lds row = u+1
                acc[0][0] = __builtin_amdgcn_mfma_f32_32x32x16_bf16(a0, b0, acc[0][0], 0, 0, 0);
                acc[0][1] = __builtin_amdgcn_mfma_f32_32x32x16_bf16(a0, b1, acc[0][1], 0, 0, 0);
                acc[1][0] = __builtin_amdgcn_mfma_f32_32x32x16_bf16(a1, b0, acc[1][0], 0, 0, 0);
                acc[1][1] = __builtin_amdgcn_mfma_f32_32x32x16_bf16(a1, b1, acc[1][1], 0, 0, 0);
            }
        }
    }

    // epilogue: C/D layout col=lane&31, row=(r&3)+8*(r>>2)+4*(lane>>5)
#pragma unroll
    for (int mi = 0; mi < 2; mi++)
#pragma unroll
    for (int ni = 0; ni < 2; ni++) {
        int p = p0 + ni;
#pragma unroll
        for (int r = 0; r < 16; r++) {
            int fl = (r & 3) + 8 * (r >> 2) + 4 * klane;
            int f = fbase + mi * 32 + fl;
            size_t idx = xb + (size_t)f * 1024 + p * 32 + qcol;
            out[idx] = acc[mi][ni][r] + x[idx] + cb[f];
        }
    }
}

extern "C" void kernel_launch(void* const* d_in, const int* in_sizes, int n_in,
                              void* d_out, int out_size, void* d_ws, size_t ws_size,
                              hipStream_t stream) {
    const float* x     = (const float*)d_in[0];
    const float* z     = (const float*)d_in[1];
    const float* dw    = (const float*)d_in[2];
    const float* db    = (const float*)d_in[3];
    const float* gamma = (const float*)d_in[4];
    const float* beta  = (const float*)d_in[5];
    const float* cb    = (const float*)d_in[6];
    float* out = (float*)d_out;

    unsigned short* wkn = (unsigned short*)d_ws;                    // 9.44 MB bf16 natural
    unsigned short* wkt = (unsigned short*)((char*)d_ws + (size_t)BSZ * NB * 2);  // 9.44 MB bf16 [b][uv][f][s]

    hyper_gemm_bn<<<NB / 256, 128, 0, stream>>>(z, dw, db, gamma, beta, wkn);
    repack<<<dim3(BSZ, 8), 256, 0, stream>>>(wkn, wkt);
    conv_mfma<<<dim3(BSZ, 16), 128, 0, stream>>>(x, wkt, cb, out);
}

// Round 3
// 307.422 us; speedup vs baseline: 2.0551x; 1.0874x over previous
//
#include <hip/hip_runtime.h>

#define NB 147456   // C*C*KH*KW per sample
#define NB2 73728
#define ZD 256
#define BSZ 32
#define CCH 128

typedef __attribute__((ext_vector_type(8))) short short8;
typedef __attribute__((ext_vector_type(16))) float floatx16;

__device__ __forceinline__ unsigned short f2bf(float f) {
    unsigned int u = __float_as_uint(f);
    return (unsigned short)((u + 0x7fffu + ((u >> 16) & 1u)) >> 16);
}

// ---- K1: h = relu(z@W+b); BN over batch; affine; -> bf16 Wk natural [b][n] --------------------
// 2 cols/thread, 16-deep double-buffered weight prefetch, z broadcast from LDS (natural layout).
__global__ __launch_bounds__(128) void hyper_gemm_bn(
    const float* __restrict__ z, const float* __restrict__ dw,
    const float* __restrict__ db, const float* __restrict__ gamma,
    const float* __restrict__ beta, unsigned short* __restrict__ wkn)
{
    __shared__ float zs[ZD * BSZ];            // natural [b][k]; reads are wave-broadcast
    int t = threadIdx.x;
    {
        const float4* z4 = (const float4*)z;
        float4* zw = (float4*)zs;
#pragma unroll
        for (int i = 0; i < 16; i++) zw[t + i * 128] = z4[t + i * 128];
    }
    __syncthreads();

    int n0 = (blockIdx.x * 128 + t) * 2;      // 576 blocks
    size_t nc = (size_t)(n0 >> 1);
    const float2* dw2 = (const float2*)dw;

    float acc0[32], acc1[32];
#pragma unroll
    for (int b = 0; b < 32; b++) { acc0[b] = 0.f; acc1[b] = 0.f; }

    const float4* zs4 = (const float4*)zs;
    float2 wc[16], wn[16];
#pragma unroll
    for (int j = 0; j < 16; j++) wc[j] = dw2[(size_t)j * NB2 + nc];

    for (int c = 0; c < 16; c++) {            // 16 k-chunks of 16
        if (c < 15) {
#pragma unroll
            for (int j = 0; j < 16; j++)
                wn[j] = dw2[(size_t)(c * 16 + 16 + j) * NB2 + nc];
        }
#pragma unroll
        for (int b = 0; b < 32; b++) {
            float4 z0 = zs4[b * 64 + c * 4 + 0];
            float4 z1 = zs4[b * 64 + c * 4 + 1];
            float4 z2 = zs4[b * 64 + c * 4 + 2];
            float4 z3 = zs4[b * 64 + c * 4 + 3];
            float zv[16] = { z0.x, z0.y, z0.z, z0.w, z1.x, z1.y, z1.z, z1.w,
                             z2.x, z2.y, z2.z, z2.w, z3.x, z3.y, z3.z, z3.w };
#pragma unroll
            for (int j = 0; j < 16; j++) {
                acc0[b] += zv[j] * wc[j].x;
                acc1[b] += zv[j] * wc[j].y;
            }
        }
#pragma unroll
        for (int j = 0; j < 16; j++) wc[j] = wn[j];
    }

    float bias0 = db[n0], bias1 = db[n0 + 1];
    float s0 = 0.f, q0 = 0.f, s1 = 0.f, q1 = 0.f;
#pragma unroll
    for (int b = 0; b < 32; b++) {
        float h0 = fmaxf(acc0[b] + bias0, 0.f); acc0[b] = h0; s0 += h0; q0 += h0 * h0;
        float h1 = fmaxf(acc1[b] + bias1, 0.f); acc1[b] = h1; s1 += h1; q1 += h1 * h1;
    }
    float m0 = s0 * (1.f/32.f), m1 = s1 * (1.f/32.f);
    float v0 = fmaxf(q0 * (1.f/32.f) - m0 * m0, 0.f);
    float v1 = fmaxf(q1 * (1.f/32.f) - m1 * m1, 0.f);
    float sc0 = gamma[n0]     / (sqrtf(v0) + 1e-6f), bt0 = beta[n0];
    float sc1 = gamma[n0 + 1] / (sqrtf(v1) + 1e-6f), bt1 = beta[n0 + 1];

    unsigned int* wout = (unsigned int*)wkn;
#pragma unroll
    for (int b = 0; b < 32; b++) {
        float w0 = sc0 * (acc0[b] - m0) + bt0;
        float w1 = sc1 * (acc1[b] - m1) + bt1;
        wout[((size_t)b * NB + n0) >> 1] = (unsigned int)f2bf(w0) | ((unsigned int)f2bf(w1) << 16);
    }
}

// ---- repack: wkn[b][s*1152 + f*9 + uv] -> wkt[b][uv][f][s] (bf16) ----------------------------
__global__ __launch_bounds__(256) void repack(
    const unsigned short* __restrict__ wkn, unsigned short* __restrict__ wkt)
{
    __shared__ unsigned int lt[16 * 580];     // 16 s-rows of 576 uints, pad to 580
    int t = threadIdx.x;
    int b = blockIdx.x;
    int s0 = blockIdx.y * 16;
    const unsigned int* src = (const unsigned int*)wkn + ((size_t)b * NB >> 1) + (size_t)s0 * 576;
#pragma unroll
    for (int i = 0; i < 36; i++) {
        int idx = t + i * 256;                // 9216 uints, row-contiguous (coalesced)
        int si = idx / 576;
        int j2 = idx - si * 576;
        lt[si * 580 + j2] = src[(size_t)si * 576 + j2];
    }
    __syncthreads();
    const unsigned short* ls = (const unsigned short*)lt;
#pragma unroll
    for (int i = 0; i < 9; i++) {
        int tau = t + i * 256;                // 2304 tasks: (uv,f,half)
        int half = tau & 1;
        int unit = tau >> 1;
        int uv = unit >> 7;
        int f = unit & 127;
        int col = f * 9 + uv;
        unsigned short v[8];
#pragma unroll
        for (int ss = 0; ss < 8; ss++)
            v[ss] = ls[(half * 8 + ss) * 1160 + col];
        uint4 o;
        o.x = v[0] | ((unsigned)v[1] << 16);
        o.y = v[2] | ((unsigned)v[3] << 16);
        o.z = v[4] | ((unsigned)v[5] << 16);
        o.w = v[6] | ((unsigned)v[7] << 16);
        ((uint4*)wkt)[((((size_t)b * 9 + uv) * 128 + f) * 16) + (s0 >> 3) + half] = o;
    }
}

// ---- x transpose: x[b][s][p][q] fp32 -> xT[b][p][q][s] bf16 ----------------------------------
__global__ __launch_bounds__(256) void x_transpose(
    const float* __restrict__ x, unsigned short* __restrict__ xb16)
{
    __shared__ unsigned short lx[32 * 130];   // [q][s], pad 130
    int t = threadIdx.x;
    int p = blockIdx.x;
    int b = blockIdx.y;
    const float* xp = x + (size_t)b * CCH * 1024 + p * 32;
#pragma unroll
    for (int i = 0; i < 16; i++) {
        int idx = t + i * 256;                // 4096: s = idx>>5, q = idx&31
        int s = idx >> 5;
        int q = idx & 31;
        lx[q * 130 + s] = f2bf(xp[(size_t)s * 1024 + q]);
    }
    __syncthreads();
#pragma unroll
    for (int i = 0; i < 2; i++) {
        int tau = t + i * 256;                // 512: q = tau>>4, chunk = tau&15
        int q = tau >> 4;
        int ch = tau & 15;
        const unsigned short* r = &lx[q * 130 + ch * 8];
        uint4 o;
        o.x = r[0] | ((unsigned)r[1] << 16);
        o.y = r[2] | ((unsigned)r[3] << 16);
        o.z = r[4] | ((unsigned)r[5] << 16);
        o.w = r[6] | ((unsigned)r[7] << 16);
        ((uint4*)xb16)[((((size_t)b * 32 + p) * 32) + q) * 16 + ch] = o;
    }
}

// ---- conv: out[b,f,p,q] = sum_uv sum_s Wuv[f,s]*x[b,s,p+u-1,q+v-1] + cb[f] + x[b,f,p,q] -------
// Block: 2 waves = 128f x 2 rows. Full K=128 in LDS (one barrier), 288 straight-line MFMAs.
__global__ __launch_bounds__(128) void conv_mfma(
    const float* __restrict__ x, const unsigned short* __restrict__ xb16,
    const unsigned short* __restrict__ wkt, const float* __restrict__ cb,
    float* __restrict__ out)
{
    __shared__ short8 lds8[4 * 34 * 17];      // [row][col][s-chunk], col stride 17 short8 (pad)
    int t = threadIdx.x;
    int p0 = blockIdx.x * 2;                  // x fastest: co-resident blocks share sample b
    int b = blockIdx.y;
    int lane = t & 63;
    int fbase = (t >> 6) * 64;
    int qcol = lane & 31;
    int klane = lane >> 5;

    {   // zero halo columns 0 and 33 (128 tasks, one per thread)
        int r = t >> 5;
        int col = ((t >> 4) & 1) ? 33 : 0;
        int ch = t & 15;
        short8 zz = { 0, 0, 0, 0, 0, 0, 0, 0 };
        lds8[(r * 34 + col) * 17 + ch] = zz;
    }
    const uint4* xsrc = (const uint4*)xb16;
#pragma unroll
    for (int i = 0; i < 16; i++) {
        int tau = t + i * 128;                // 2048 uint4: rows p0-1..p0+2, cols 0..31, ch 0..15
        int ch = tau & 15;
        int q = (tau >> 4) & 31;
        int r = tau >> 9;
        int prow = p0 - 1 + r;
        uint4 v = make_uint4(0, 0, 0, 0);
        if (prow >= 0 && prow < 32)
            v = xsrc[((((size_t)b * 32 + prow) * 32) + q) * 16 + ch];
        *(uint4*)&lds8[(r * 34 + q + 1) * 17 + ch] = v;
    }
    __syncthreads();

    floatx16 acc[2][2];
#pragma unroll
    for (int mi = 0; mi < 2; mi++)
#pragma unroll
        for (int ni = 0; ni < 2; ni++)
#pragma unroll
            for (int r = 0; r < 16; r++) acc[mi][ni][r] = 0.f;

    const short8* A8 = (const short8*)wkt;
#pragma unroll
    for (int u = 0; u < 3; u++)
#pragma unroll
    for (int v = 0; v < 3; v++) {
        int uvi = u * 3 + v;
        const short8* Au = A8 + ((size_t)(b * 9 + uvi) << 11);   // *128f*16chunks
#pragma unroll
        for (int ks = 0; ks < 8; ks++) {
            int koff = ks * 2 + klane;
            short8 a0 = Au[(fbase + qcol) * 16 + koff];
            short8 a1 = Au[(fbase + 32 + qcol) * 16 + koff];
            short8 b0 = lds8[(u * 34 + qcol + v) * 17 + koff];
            short8 b1 = lds8[((u + 1) * 34 + qcol + v) * 17 + koff];
            acc[0][0] = __builtin_amdgcn_mfma_f32_32x32x16_bf16(a0, b0, acc[0][0], 0, 0, 0);
            acc[0][1] = __builtin_amdgcn_mfma_f32_32x32x16_bf16(a0, b1, acc[0][1], 0, 0, 0);
            acc[1][0] = __builtin_amdgcn_mfma_f32_32x32x16_bf16(a1, b0, acc[1][0], 0, 0, 0);
            acc[1][1] = __builtin_amdgcn_mfma_f32_32x32x16_bf16(a1, b1, acc[1][1], 0, 0, 0);
        }
    }

    const size_t xb = (size_t)b * CCH * 1024;
#pragma unroll
    for (int mi = 0; mi < 2; mi++)
#pragma unroll
    for (int ni = 0; ni < 2; ni++) {
        int p = p0 + ni;
#pragma unroll
        for (int r = 0; r < 16; r++) {
            int fl = (r & 3) + 8 * (r >> 2) + 4 * klane;
            int f = fbase + mi * 32 + fl;
            size_t idx = xb + (size_t)f * 1024 + p * 32 + qcol;
            out[idx] = acc[mi][ni][r] + x[idx] + cb[f];
        }
    }
}

extern "C" void kernel_launch(void* const* d_in, const int* in_sizes, int n_in,
                              void* d_out, int out_size, void* d_ws, size_t ws_size,
                              hipStream_t stream) {
    const float* x     = (const float*)d_in[0];
    const float* z     = (const float*)d_in[1];
    const float* dw    = (const float*)d_in[2];
    const float* db    = (const float*)d_in[3];
    const float* gamma = (const float*)d_in[4];
    const float* beta  = (const float*)d_in[5];
    const float* cb    = (const float*)d_in[6];
    float* out = (float*)d_out;

    unsigned short* wkn = (unsigned short*)d_ws;                                   // 9.44 MB
    unsigned short* wkt = (unsigned short*)((char*)d_ws + (size_t)BSZ * NB * 2);   // 9.44 MB
    unsigned short* xb16 = wkn;   // alias: wkn fully consumed by repack before x_transpose runs

    hyper_gemm_bn<<<NB / 256, 128, 0, stream>>>(z, dw, db, gamma, beta, wkn);
    repack<<<dim3(BSZ, 8), 256, 0, stream>>>(wkn, wkt);
    x_transpose<<<dim3(32, BSZ), 256, 0, stream>>>(x, xb16);
    conv_mfma<<<dim3(16, BSZ), 128, 0, stream>>>(x, xb16, wkt, cb, out);
}